// Round 1
// baseline (110.303 us; speedup 1.0000x reference)
//
#include <hip/hip_runtime.h>
#include <math.h>

// LRU (Laguerre ladder) recurrence, MI355X.
// B=32, T=512, I=64, F=64, H=64. Output: (B,T,F,H) f32 then h_final (F,B,H) f32.
#define TT 512
#define FF 64
#define BB 32
#define HH 64

#define NSLOT 32            // ring rows per chain (power of 2)
#define RS    72            // ring row stride in floats (72%32==8 -> bank spread)
#define GS    (NSLOT*RS + 8) // per-chain-group ring stride = 2312 floats
#define US    520           // u row stride (520%32==8 -> bank spread)

__device__ __forceinline__ float dpp_row_shr1(float v) {
    // lane r in each 16-lane row reads lane r-1; lane 0 of each row -> 0 (bound_ctrl)
    int r = __builtin_amdgcn_update_dpp(0, __float_as_int(v), 0x111, 0xf, 0xf, true);
    return __int_as_float(r);
}

__global__ __launch_bounds__(64) void lru_kernel(
    const float* __restrict__ x,      // (B,T,I)
    const float* __restrict__ W,      // (F,I)
    const float* __restrict__ relax,  // (F,)
    float* __restrict__ out)          // (B,T,F,H) ++ (F,B,H)
{
    __shared__ float u_lds[4 * US];   // u[t] per chain group, 8.3 KB
    __shared__ float ring[4 * GS];    // output transpose ring, 37 KB

    const int w  = blockIdx.x;        // 512 waves total
    const int b  = w >> 4;            // batch
    const int f0 = (w & 15) << 2;     // first of 4 consecutive filterbanks
    const int l  = threadIdx.x;
    const int j  = l & 15;            // lane within chain (owns i = 4j..4j+3)
    const int g  = l >> 4;            // chain group 0..3 (f = f0+g)

    // ---------------- phase 1: u[g][t] = dot(x[b,t,:], W[f0+g,:]) ----------------
    const float4* Wv = reinterpret_cast<const float4*>(W) + (size_t)f0 * 16;
    for (int c = 0; c < 8; ++c) {
        const int t = (c << 6) + l;   // each lane one t, all 4 f's
        const float4* xv = reinterpret_cast<const float4*>(x) + ((size_t)b * TT + t) * 16;
        float a0 = 0.f, a1 = 0.f, a2 = 0.f, a3 = 0.f;
        #pragma unroll
        for (int q = 0; q < 16; ++q) {
            const float4 xq = xv[q];
            const float4 w0 = Wv[q];
            const float4 w1 = Wv[16 + q];
            const float4 w2 = Wv[32 + q];
            const float4 w3 = Wv[48 + q];
            a0 = fmaf(xq.x, w0.x, fmaf(xq.y, w0.y, fmaf(xq.z, w0.z, fmaf(xq.w, w0.w, a0))));
            a1 = fmaf(xq.x, w1.x, fmaf(xq.y, w1.y, fmaf(xq.z, w1.z, fmaf(xq.w, w1.w, a1))));
            a2 = fmaf(xq.x, w2.x, fmaf(xq.y, w2.y, fmaf(xq.z, w2.z, fmaf(xq.w, w2.w, a2))));
            a3 = fmaf(xq.x, w3.x, fmaf(xq.y, w3.y, fmaf(xq.z, w3.z, fmaf(xq.w, w3.w, a3))));
        }
        u_lds[0 * US + t] = a0;
        u_lds[1 * US + t] = a1;
        u_lds[2 * US + t] = a2;
        u_lds[3 * US + t] = a3;
    }
    __syncthreads();

    // ---------------- phase 2: skewed recurrence ----------------
    const float rel = relax[f0 + g];
    const float a   = sqrtf(rel);
    const float gn  = sqrtf(1.0f - rel);
    const bool  isj0 = (j == 0);
    const float cA  = isj0 ? gn : a;  // coefficient on the "incoming" value

    float prev0 = 0.f, prev1 = 0.f, prev2 = 0.f, prev3 = 0.f;  // y[t-1][4j..4j+3]
    float nbr_prev = 0.f;             // y[t-1][4j-1]
    float v3 = 0.f;                   // last computed y[t][4j+3] (DPP source)
    int   t  = -j;                    // this lane's timestep at iteration k

    float*       ringg = ring  + g * GS;
    const float* ug    = u_lds + g * US;
    float u_t = ug[0];

    float* outrow = out + (size_t)b * (TT * FF * HH) + (size_t)(f0 + g) * HH + 4 * j;
    float* hfin   = out + (size_t)BB * TT * FF * HH
                        + ((size_t)(f0 + g) * BB + b) * HH + 4 * j;

    for (int k = 0; k < TT + 16; ++k) {
        // ---- flush row tf = k-16 (complete since iter k-1); coalesced 1KB store ----
        const int tf = k - 16;
        float r0, r1, r2, r3;
        if (tf >= 0) {
            const int off = (tf & (NSLOT - 1)) * RS + j;
            r0 = ringg[off];
            r1 = ringg[off + 16];
            r2 = ringg[off + 32];
            r3 = ringg[off + 48];
        }

        // ---- compute y[t][4j..4j+3] ----
        const float shifted = dpp_row_shr1(v3);          // y[t][4j-1] from lane j-1
        const float nbr_cur = isj0 ? u_t : shifted;
        float v0  = fmaf(cA, nbr_cur, fmaf(a, prev0, -nbr_prev));
        float v1  = fmaf(a, v0, fmaf(a, prev1, -prev0));
        float v2  = fmaf(a, v1, fmaf(a, prev2, -prev1));
        float vv3 = fmaf(a, v2, fmaf(a, prev3, -prev2));

        const bool live = ((unsigned)t < (unsigned)TT);  // freeze before start / after end
        v0  = live ? v0  : prev0;
        v1  = live ? v1  : prev1;
        v2  = live ? v2  : prev2;
        vv3 = live ? vv3 : prev3;

        if (live) {  // ring write: col 4j+i at position 16*i + j (bank-spread)
            const int woff = (t & (NSLOT - 1)) * RS + j;
            ringg[woff]      = v0;
            ringg[woff + 16] = v1;
            ringg[woff + 32] = v2;
            ringg[woff + 48] = vv3;
        }

        prev0 = v0; prev1 = v1; prev2 = v2; prev3 = vv3;
        nbr_prev = isj0 ? 0.f : nbr_cur;
        v3 = vv3;
        ++t;

        // prefetch u for next iteration (hide LDS latency)
        const int kn = (k + 1 < TT) ? (k + 1) : (TT - 1);
        u_t = ug[kn];

        if (tf >= 0) {
            float4 o; o.x = r0; o.y = r1; o.z = r2; o.w = r3;
            *reinterpret_cast<float4*>(outrow + (size_t)tf * (FF * HH)) = o;
        }
    }

    // ---- h_final = y[T-1] (frozen in prev regs) ----
    float4 hf; hf.x = prev0; hf.y = prev1; hf.z = prev2; hf.w = prev3;
    *reinterpret_cast<float4*>(hfin) = hf;
}

extern "C" void kernel_launch(void* const* d_in, const int* in_sizes, int n_in,
                              void* d_out, int out_size, void* d_ws, size_t ws_size,
                              hipStream_t stream) {
    const float* x     = (const float*)d_in[0];
    const float* W     = (const float*)d_in[1];
    const float* relax = (const float*)d_in[2];
    float* out = (float*)d_out;
    lru_kernel<<<dim3(512), dim3(64), 0, stream>>>(x, W, relax, out);
}

// Round 2
// 104.110 us; speedup vs baseline: 1.0595x; 1.0595x over previous
//
#include <hip/hip_runtime.h>
#include <math.h>

// LRU (Laguerre ladder) recurrence, MI355X.
// B=32, T=512, I=64, F=64, H=64. Output: (B,T,F,H) f32 ++ h_final (F,B,H) f32.
// One (b,f) chain per 64-lane wave; lane l owns hidden index l; wavefront-skew
// over t (lane l at timestep t = k - l). 2048 blocks -> 8 waves/CU.
#define TT 512
#define FF 64
#define BB 32
#define HH 64

#define NSLOT 64   // ring slots (== skew span; same-slot reuse safe: read precedes write in-wave)
#define RS    66   // ring row stride in floats (66 % 32 == 2 -> bank rotation, 2-way max = free)

// shift value from lane l-1 to lane l across the whole wave:
// row_shr:1 within 16-lane rows; row_bcast:15 fills lanes 16/32/48 from 15/31/47.
__device__ __forceinline__ float shift_up1(float v, int j16) {
    int s1 = __builtin_amdgcn_update_dpp(0, __float_as_int(v), 0x111, 0xf, 0xf, true);  // row_shr:1
    int s2 = __builtin_amdgcn_update_dpp(0, __float_as_int(v), 0x142, 0xf, 0xf, false); // row_bcast:15
    return __int_as_float((j16 == 0) ? s2 : s1);
}

__global__ __launch_bounds__(64) void lru_kernel(
    const float* __restrict__ x,      // (B,T,I)
    const float* __restrict__ W,      // (F,I)
    const float* __restrict__ relax,  // (F,)
    float* __restrict__ out)          // (B,T,F,H) ++ (F,B,H)
{
    __shared__ float u_lds[TT + 16];      // 2.1 KB
    __shared__ float ring[NSLOT * RS];    // 16.9 KB

    const int w = blockIdx.x;             // 2048 waves
    const int b = w >> 6;                 // batch
    const int f = w & 63;                 // filterbank
    const int l = threadIdx.x;            // hidden index owned by this lane
    const int j16 = l & 15;

    // ---------------- phase 1: u[t] = dot(x[b,t,:], W[f,:]) ----------------
    const float4* __restrict__ Wv = reinterpret_cast<const float4*>(W) + (size_t)f * 16;
    float4 wreg[16];
    #pragma unroll
    for (int q = 0; q < 16; ++q) wreg[q] = Wv[q];
    const float4* __restrict__ xb = reinterpret_cast<const float4*>(x) + (size_t)b * TT * 16;
    #pragma unroll
    for (int c = 0; c < 8; ++c) {
        const int t = (c << 6) + l;       // each lane one t
        const float4* xv = xb + (size_t)t * 16;
        float acc = 0.f;
        #pragma unroll
        for (int q = 0; q < 16; ++q) {
            const float4 xq = xv[q], wq = wreg[q];
            acc = fmaf(xq.x, wq.x, fmaf(xq.y, wq.y, fmaf(xq.z, wq.z, fmaf(xq.w, wq.w, acc))));
        }
        u_lds[t] = acc;
    }
    __syncthreads();

    // ---------------- phase 2: skewed recurrence ----------------
    const float rel = relax[f];
    const float a  = sqrtf(rel);
    const float gn = sqrtf(1.0f - rel);
    const bool isj0 = (l == 0);
    const float cA = isj0 ? gn : a;       // coefficient on the incoming value

    float prev = 0.f;                     // y[t-1][l]
    float nbr_prev = 0.f;                 // y[t-1][l-1]
    float vlast = 0.f;                    // y[t][l] as DPP source
    float u_t = u_lds[0];

    float* outcol = out + (size_t)b * (TT * FF * HH) + (size_t)f * HH + l;
    float* hfin   = out + (size_t)BB * TT * FF * HH + ((size_t)f * BB + b) * HH + l;

    #pragma unroll 8
    for (int k = 0; k < TT + 64; ++k) {
        // ---- flush row tf = k-64 (lane 63 completed it at iteration k-1) ----
        const int tf = k - 64;
        float r0 = 0.f;
        if (tf >= 0) r0 = ring[(tf & (NSLOT - 1)) * RS + l];

        // ---- compute y[t][l], t = k - l ----
        const int t = k - l;
        const float shifted = shift_up1(vlast, j16);  // y[t][l-1] from lane l-1 (iter k-1)
        const float nbr_cur = isj0 ? u_t : shifted;
        float v = fmaf(cA, nbr_cur, fmaf(a, prev, -nbr_prev));

        const bool live = ((unsigned)t < (unsigned)TT);
        v = live ? v : prev;                           // freeze outside [0,TT)
        if (live) ring[((unsigned)t & (NSLOT - 1)) * RS + l] = v;

        prev = v;
        nbr_prev = isj0 ? 0.f : nbr_cur;
        vlast = v;

        // prefetch u for next iteration (only lane 0 consumes; broadcast read)
        const int kn = (k + 1 < TT) ? (k + 1) : (TT - 1);
        u_t = u_lds[kn];

        if (tf >= 0) outcol[(size_t)tf * (FF * HH)] = r0;  // 256 B coalesced wave store
    }

    // ---- h_final = y[T-1][l] ----
    *hfin = prev;
}

extern "C" void kernel_launch(void* const* d_in, const int* in_sizes, int n_in,
                              void* d_out, int out_size, void* d_ws, size_t ws_size,
                              hipStream_t stream) {
    const float* x     = (const float*)d_in[0];
    const float* W     = (const float*)d_in[1];
    const float* relax = (const float*)d_in[2];
    float* out = (float*)d_out;
    lru_kernel<<<dim3(2048), dim3(64), 0, stream>>>(x, W, relax, out);
}

// Round 3
// 86.496 us; speedup vs baseline: 1.2752x; 1.2036x over previous
//
#include <hip/hip_runtime.h>
#include <math.h>

// LRU (Laguerre ladder) recurrence, MI355X.
// B=32, T=512, I=64, F=64, H=64. Output: (B,T,F,H) f32 ++ h_final (F,B,H) f32.
// One (b,f) chain per 64-lane wave, lane l owns hidden index l, wavefront-skew
// over t. Superstep structure: 32 compute iters + chunked b128 flush + 1KB stores.
#define TT 512
#define FF 64
#define BB 32
#define HH 64
#define NSLOT 128   // ring slots (pow2; >= 96 live span -> no aliasing, frozen writes safe)
#define RS   68     // ring row stride in floats (272B = 17*16B aligned, +4 bank rotation)

__device__ __forceinline__ float shift_up1(float v, int j16) {
    // lane l gets lane l-1's value across the whole wave
    int s1 = __builtin_amdgcn_update_dpp(0, __float_as_int(v), 0x111, 0xf, 0xf, true);  // row_shr:1
    int s2 = __builtin_amdgcn_update_dpp(0, __float_as_int(v), 0x142, 0xf, 0xf, false); // row_bcast:15
    return __int_as_float((j16 == 0) ? s2 : s1);
}

// one recurrence step; MASKED is a compile-time constant
#define STEP(MASKED, UK) do {                                          \
    const float shifted = shift_up1(vlast, j16);                       \
    const float nbr_cur = isj0 ? (UK) : shifted;                       \
    float v = fmaf(cA, nbr_cur, fmaf(a, prev, -nbr_prev));             \
    if (MASKED) { v = (((unsigned)t < (unsigned)TT) ? v : prev); }     \
    ring[ws * RS + l] = v;                                             \
    ws = (ws + 1) & (NSLOT - 1);                                       \
    ++t;                                                               \
    prev = v; vlast = v;                                               \
    nbr_prev = isj0 ? 0.f : nbr_cur;                                   \
} while (0)

#define SUPERSTEP(S, MASKED) do {                                      \
    if (((S) & 1) == 0) {                                              \
        const int c1 = ((S) >> 1) + 1;                                 \
        u_nxt = u_lds[(c1 << 6) + l];     /* c1<=9 -> idx<=639 */      \
    }                                                                  \
    const int q = (S) - 3;                                             \
    float4 f0, f1, f2, f3, f4, f5, f6, f7;                             \
    if (q >= 0) {                                                      \
        const float* rp = ring + (((q & 3) << 5) + (l >> 4)) * RS + (j16 << 2); \
        f0 = *(const float4*)(rp + 0 * 4 * RS);                        \
        f1 = *(const float4*)(rp + 1 * 4 * RS);                        \
        f2 = *(const float4*)(rp + 2 * 4 * RS);                        \
        f3 = *(const float4*)(rp + 3 * 4 * RS);                        \
        f4 = *(const float4*)(rp + 4 * 4 * RS);                        \
        f5 = *(const float4*)(rp + 5 * 4 * RS);                        \
        f6 = *(const float4*)(rp + 6 * 4 * RS);                        \
        f7 = *(const float4*)(rp + 7 * 4 * RS);                        \
    }                                                                  \
    _Pragma("unroll")                                                  \
    for (int i = 0; i < 16; ++i) {                                     \
        const int li = (((S) & 1) << 5) + i;                           \
        const float u_k = __int_as_float(                              \
            __builtin_amdgcn_readlane(__float_as_int(u_cur), li));     \
        STEP(MASKED, u_k);                                             \
    }                                                                  \
    if (q >= 0) {                                                      \
        float* op = outb + (size_t)((q << 5) + (l >> 4)) * (FF * HH) + (j16 << 2); \
        *(float4*)(op + (size_t)0 * 4 * FF * HH) = f0;                 \
        *(float4*)(op + (size_t)1 * 4 * FF * HH) = f1;                 \
        *(float4*)(op + (size_t)2 * 4 * FF * HH) = f2;                 \
        *(float4*)(op + (size_t)3 * 4 * FF * HH) = f3;                 \
        *(float4*)(op + (size_t)4 * 4 * FF * HH) = f4;                 \
        *(float4*)(op + (size_t)5 * 4 * FF * HH) = f5;                 \
        *(float4*)(op + (size_t)6 * 4 * FF * HH) = f6;                 \
        *(float4*)(op + (size_t)7 * 4 * FF * HH) = f7;                 \
    }                                                                  \
    _Pragma("unroll")                                                  \
    for (int i = 16; i < 32; ++i) {                                    \
        const int li = (((S) & 1) << 5) + i;                           \
        const float u_k = __int_as_float(                              \
            __builtin_amdgcn_readlane(__float_as_int(u_cur), li));     \
        STEP(MASKED, u_k);                                             \
    }                                                                  \
    if (((S) & 1) == 1) u_cur = u_nxt;                                 \
} while (0)

__global__ __launch_bounds__(64) void lru_kernel(
    const float* __restrict__ x,      // (B,T,I)
    const float* __restrict__ W,      // (F,I)
    const float* __restrict__ relax,  // (F,)
    float* __restrict__ out)          // (B,T,F,H) ++ (F,B,H)
{
    __shared__ float u_lds[640];          // 2.5 KB (512 used; tail read-but-unused)
    __shared__ float ring[NSLOT * RS];    // 34 KB

    const int w = blockIdx.x;             // 2048 waves
    const int b = w >> 6;
    const int f = w & 63;
    const int l = threadIdx.x;
    const int j16 = l & 15;

    // ---------------- phase 1: u[t] = dot(x[b,t,:], W[f,:]) ----------------
    {
        const float4* __restrict__ Wv = reinterpret_cast<const float4*>(W) + (size_t)f * 16;
        float4 wreg[16];
        #pragma unroll
        for (int q = 0; q < 16; ++q) wreg[q] = Wv[q];
        const float4* __restrict__ xb = reinterpret_cast<const float4*>(x) + (size_t)b * TT * 16;
        #pragma unroll
        for (int c = 0; c < 8; ++c) {
            const int tt = (c << 6) + l;
            const float4* xv = xb + (size_t)tt * 16;
            float acc = 0.f;
            #pragma unroll
            for (int q = 0; q < 16; ++q) {
                const float4 xq = xv[q], wq = wreg[q];
                acc = fmaf(xq.x, wq.x, fmaf(xq.y, wq.y, fmaf(xq.z, wq.z, fmaf(xq.w, wq.w, acc))));
            }
            u_lds[tt] = acc;              // lane l writes/reads only index (c<<6)+l
        }
    }
    __syncthreads();

    // ---------------- phase 2: skewed recurrence, superstep-structured ----------------
    const float rel = relax[f];
    const float a  = sqrtf(rel);
    const float gn = sqrtf(1.0f - rel);
    const bool isj0 = (l == 0);
    const float cA = isj0 ? gn : a;

    float prev = 0.f, nbr_prev = 0.f, vlast = 0.f;
    int t  = -l;                          // lane's timestep at iteration k
    int ws = (NSLOT - l) & (NSLOT - 1);   // slot of row t (t mod NSLOT)

    float u_cur = u_lds[l];               // u[0..63] in lanes (c=0)
    float u_nxt = 0.f;

    float* const outb = out + (size_t)b * (TT * FF * HH) + (size_t)f * HH;

    for (int s = 0; s < 2; ++s)   SUPERSTEP(s, true);   // ramp-in (mask t<0)
    for (int s = 2; s < 16; ++s)  SUPERSTEP(s, false);  // steady: all lanes live
    for (int s = 16; s < 18; ++s) SUPERSTEP(s, true);   // ramp-out (mask t>=T)

    // tail flush: chunk 15 (rows 480..511), complete at end of s=17
    {
        const float* rp = ring + (((15 & 3) << 5) + (l >> 4)) * RS + (j16 << 2);
        float4 f0 = *(const float4*)(rp + 0 * 4 * RS);
        float4 f1 = *(const float4*)(rp + 1 * 4 * RS);
        float4 f2 = *(const float4*)(rp + 2 * 4 * RS);
        float4 f3 = *(const float4*)(rp + 3 * 4 * RS);
        float4 f4 = *(const float4*)(rp + 4 * 4 * RS);
        float4 f5 = *(const float4*)(rp + 5 * 4 * RS);
        float4 f6 = *(const float4*)(rp + 6 * 4 * RS);
        float4 f7 = *(const float4*)(rp + 7 * 4 * RS);
        float* op = outb + (size_t)((15 << 5) + (l >> 4)) * (FF * HH) + (j16 << 2);
        *(float4*)(op + (size_t)0 * 4 * FF * HH) = f0;
        *(float4*)(op + (size_t)1 * 4 * FF * HH) = f1;
        *(float4*)(op + (size_t)2 * 4 * FF * HH) = f2;
        *(float4*)(op + (size_t)3 * 4 * FF * HH) = f3;
        *(float4*)(op + (size_t)4 * 4 * FF * HH) = f4;
        *(float4*)(op + (size_t)5 * 4 * FF * HH) = f5;
        *(float4*)(op + (size_t)6 * 4 * FF * HH) = f6;
        *(float4*)(op + (size_t)7 * 4 * FF * HH) = f7;
    }

    // ---- h_final = y[T-1][l] (frozen in prev) ----
    out[(size_t)BB * TT * FF * HH + ((size_t)f * BB + b) * HH + l] = prev;
}

extern "C" void kernel_launch(void* const* d_in, const int* in_sizes, int n_in,
                              void* d_out, int out_size, void* d_ws, size_t ws_size,
                              hipStream_t stream) {
    const float* x     = (const float*)d_in[0];
    const float* W     = (const float*)d_in[1];
    const float* relax = (const float*)d_in[2];
    float* out = (float*)d_out;
    lru_kernel<<<dim3(2048), dim3(64), 0, stream>>>(x, W, relax, out);
}

// Round 6
// 81.601 us; speedup vs baseline: 1.3517x; 1.0600x over previous
//
#include <hip/hip_runtime.h>
#include <math.h>

// LRU (Laguerre ladder) recurrence, MI355X.
// B=32, T=512, I=64, F=64, H=64. Output: (B,T,F,H) f32 ++ h_final (F,B,H) f32.
// One (b,f) chain per 64-lane wave; lane l owns hidden index l; wavefront-skew
// over t (lane l computes row t = k - l at global step k).
// Ring: 96 slots x 64 floats = 24 KB LDS -> 6 blocks/CU.
// Flush: 16-row chunks; chunk q is ds_read at k = 16q+86 (margin 8 after lane-63
// completes row 16q+15 at k=16q+78; margin 10 before slot reuse at k=16q+96),
// stored to HBM 16 STEPs later via ping-pong register sets A/B.
// u[] lives in 8 VGPRs, broadcast by readlane with compile-time pair index.
// Ring writes are conditional on live (r2/r3-verified ramp semantics).
// r6 fix vs r5: READS register i reads row (l>>4)+4i (offset i*4*RSF), not
// (l>>4)+16i — r4/r5 flushed partially-written/garbage rows (inf/NaN).
#define TT 512
#define FF 64
#define BB 32
#define HH 64
#define NSLOT 96
#define RSF 64                       // floats per ring row

__device__ __forceinline__ float shift_up1(float v, int j16) {
    // lane l gets lane l-1's value across the whole wave
    int s1 = __builtin_amdgcn_update_dpp(0, __float_as_int(v), 0x111, 0xf, 0xf, true);  // row_shr:1
    int s2 = __builtin_amdgcn_update_dpp(0, __float_as_int(v), 0x142, 0xf, 0xf, false); // row_bcast:15
    return __int_as_float((j16 == 0) ? s2 : s1);
}

// one recurrence step; MASKED is a compile-time literal
#define STEP(MASKED, UK) do {                                          \
    const float shifted_ = shift_up1(vlast, j16);                      \
    const float nbr_cur_ = isj0 ? (UK) : shifted_;                     \
    float v_ = fmaf(cA, nbr_cur_, fmaf(a, prev, -nbr_prev));           \
    if (MASKED) {                                                      \
        const bool live_ = ((unsigned)t < (unsigned)TT);               \
        v_ = live_ ? v_ : prev;                                        \
        if (live_) *(float*)((char*)ring + vaddr) = v_;                \
    } else {                                                           \
        *(float*)((char*)ring + vaddr) = v_;                           \
    }                                                                  \
    vaddr += 256; vaddr = (vaddr == vtop) ? vbase : vaddr;             \
    nbr_prev = isj0 ? 0.f : nbr_cur_;                                  \
    prev = v_; vlast = v_;                                             \
    ++t;                                                               \
} while (0)

// read next chunk (16 rows) from ring into a float4 set + capture its out ptr.
// Register i holds row (l>>4) + 4*i of the chunk, cols 4*j16..4*j16+3.
#define READS(G0, G1, G2, G3, OPP) do {                                \
    const float* rp_ = ring + (sb + (l >> 4)) * RSF + (j16 << 2);      \
    G0 = *(const float4*)(rp_ + 0 * 4 * RSF);                          \
    G1 = *(const float4*)(rp_ + 1 * 4 * RSF);                          \
    G2 = *(const float4*)(rp_ + 2 * 4 * RSF);                          \
    G3 = *(const float4*)(rp_ + 3 * 4 * RSF);                          \
    OPP = ochunk + ((size_t)(l >> 4) << 12) + (j16 << 2);              \
    ochunk += 16 * 4096;                                               \
    sb += 16; if (sb == NSLOT) sb = 0;                                 \
} while (0)

// register i goes to t = chunk_base + (l>>4) + 4*i  (out t-stride = 4096 floats)
#define STORES(G0, G1, G2, G3, OPP) do {                               \
    *(float4*)(OPP + (size_t)0 * 16384) = G0;                          \
    *(float4*)(OPP + (size_t)1 * 16384) = G1;                          \
    *(float4*)(OPP + (size_t)2 * 16384) = G2;                          \
    *(float4*)(OPP + (size_t)3 * 16384) = G3;                          \
} while (0)

#define PT_RD_A do { READS(gA0,gA1,gA2,gA3, opA); } while (0)
#define PT_AB   do { STORES(gA0,gA1,gA2,gA3, opA); READS(gB0,gB1,gB2,gB3, opB); } while (0)
#define PT_BA   do { STORES(gB0,gB1,gB2,gB3, opB); READS(gA0,gA1,gA2,gA3, opA); } while (0)
#define NOPT    do {} while (0)

// one 32-STEP half; flush points after STEP i_=6 and i_=22 (k = 16q+86 pattern)
#define HALF(UREG, HS, MASKED, P6, P22) do {                           \
    _Pragma("unroll")                                                  \
    for (int i_ = 0; i_ < 32; ++i_) {                                  \
        const float uk_ = __int_as_float(                              \
            __builtin_amdgcn_readlane(__float_as_int(UREG), (HS) * 32 + i_)); \
        STEP(MASKED, uk_);                                             \
        if (i_ == 6)  { P6; }                                          \
        if (i_ == 22) { P22; }                                         \
    }                                                                  \
} while (0)

// steady pair: 4 flush points, uniform {store A, read B} / {store B, read A}
#define PAIR_STEADY(UREG) do {                                         \
    HALF(UREG, 0, false, PT_AB, PT_BA);                                \
    HALF(UREG, 1, false, PT_AB, PT_BA);                                \
} while (0)

__global__ __launch_bounds__(64) void lru_kernel(
    const float* __restrict__ x,      // (B,T,I)
    const float* __restrict__ W,      // (F,I)
    const float* __restrict__ relax,  // (F,)
    float* __restrict__ out)          // (B,T,F,H) ++ (F,B,H)
{
    __shared__ float ring[NSLOT * RSF];   // 24576 B -> 6 blocks/CU

    const int w = blockIdx.x;             // 2048 waves, one per (b,f) chain
    const int b = w >> 6;
    const int f = w & 63;
    const int l = threadIdx.x;            // hidden index owned by this lane
    const int j16 = l & 15;

    // ---------- phase 1: u[c*64+l] = dot(x[b,c*64+l,:], W[f,:]) into 8 VGPRs ----------
    float ua[8];
    {
        const float4* __restrict__ Wv = reinterpret_cast<const float4*>(W) + (size_t)f * 16;
        float4 wreg[16];
        #pragma unroll
        for (int q = 0; q < 16; ++q) wreg[q] = Wv[q];
        const float4* __restrict__ xb = reinterpret_cast<const float4*>(x) + (size_t)b * TT * 16;
        #pragma unroll
        for (int c = 0; c < 8; ++c) {
            const int tt = (c << 6) + l;
            const float4* xv = xb + (size_t)tt * 16;
            float acc = 0.f;
            #pragma unroll
            for (int q = 0; q < 16; ++q) {
                const float4 xq = xv[q], wq = wreg[q];
                acc = fmaf(xq.x, wq.x, fmaf(xq.y, wq.y, fmaf(xq.z, wq.z, fmaf(xq.w, wq.w, acc))));
            }
            ua[c] = acc;
        }
    }

    // ---------- phase 2: skewed recurrence ----------
    const float rel = relax[f];
    const float a  = sqrtf(rel);
    const float gn = sqrtf(1.0f - rel);
    const bool isj0 = (l == 0);
    const float cA = isj0 ? gn : a;

    float prev = 0.f, nbr_prev = 0.f, vlast = 0.f;
    int t = -l;                            // lane's timestep; advances every STEP

    const int vbase = l << 2;
    const int vtop  = NSLOT * 256 + vbase;
    int vaddr = ((NSLOT - l) % NSLOT) * 256 + vbase;   // slot (t mod 96), col l

    int sb = 0;                            // ring slot base of next chunk to read
    float* ochunk = out + (size_t)b * (TT * FF * HH) + (size_t)f * HH;
    float4 gA0, gA1, gA2, gA3, gB0, gB1, gB2, gB3;
    float *opA = nullptr, *opB = nullptr;

    // pair 0 (k=0..63): masked ramp-in, ring fills, no flush
    HALF(ua[0], 0, true, NOPT, NOPT);
    HALF(ua[0], 1, true, NOPT, NOPT);

    // pair 1 (k=64..127): first read at k=86 (chunk 0), then steady pattern
    HALF(ua[1], 0, false, NOPT, PT_RD_A);
    HALF(ua[1], 1, false, PT_AB, PT_BA);

    // pairs 2..7 (k=128..511): steady state, 4 chunks per pair
    PAIR_STEADY(ua[2]);
    PAIR_STEADY(ua[3]);
    PAIR_STEADY(ua[4]);
    PAIR_STEADY(ua[5]);
    PAIR_STEADY(ua[6]);
    PAIR_STEADY(ua[7]);

    // pair 8 (k=512..575): masked ramp-out; flushes chunks 27..30 (u unused by live lanes)
    HALF(ua[7], 0, true, PT_AB, PT_BA);
    HALF(ua[7], 1, true, PT_AB, PT_BA);

    // post-loop: store chunk 30 (in A), then read+store chunk 31 (all writes done)
    STORES(gA0, gA1, gA2, gA3, opA);
    READS(gB0, gB1, gB2, gB3, opB);
    STORES(gB0, gB1, gB2, gB3, opB);

    // h_final = y[T-1][l] (frozen in prev)
    out[(size_t)BB * TT * FF * HH + ((size_t)f * BB + b) * HH + l] = prev;
}

extern "C" void kernel_launch(void* const* d_in, const int* in_sizes, int n_in,
                              void* d_out, int out_size, void* d_ws, size_t ws_size,
                              hipStream_t stream) {
    const float* x     = (const float*)d_in[0];
    const float* W     = (const float*)d_in[1];
    const float* relax = (const float*)d_in[2];
    float* out = (float*)d_out;
    lru_kernel<<<dim3(2048), dim3(64), 0, stream>>>(x, W, relax, out);
}